// Round 1
// baseline (537.109 us; speedup 1.0000x reference)
//
#include <hip/hip_runtime.h>

#define N_NODES 100000
#define N_EDGES 1200000
#define D 64

// ---------------------------------------------------------------------------
// Kernel 1: h[n][o] = sum_k x[n][k] * W[o][k] + b[o]
// One wave (64 lanes) per node; lane = output feature o.
// W (64x64 = 16KB) staged in LDS; x row staged in LDS per node.
// All inner-loop LDS reads are wave-uniform -> broadcast, conflict-free.
// ---------------------------------------------------------------------------
__global__ __launch_bounds__(256) void linear_kernel(
    const float* __restrict__ x, const float* __restrict__ W,
    const float* __restrict__ b, float* __restrict__ h, int n_nodes) {
    __shared__ float Ws[D * D];
    __shared__ float xs[4][D];

    int tid = threadIdx.x;
    // cooperative load of W (4096 floats) with float4 (256 threads * 4 = 1024/iter)
    for (int i = tid * 4; i < D * D; i += 256 * 4) {
        *reinterpret_cast<float4*>(&Ws[i]) =
            *reinterpret_cast<const float4*>(&W[i]);
    }
    int sub  = tid >> 6;   // wave id within block = node slot
    int lane = tid & 63;   // output feature
    int node = blockIdx.x * 4 + sub;

    float xv = (node < n_nodes) ? x[node * D + lane] : 0.0f;
    xs[sub][lane] = xv;
    __syncthreads();

    if (node < n_nodes) {
        float acc = b[lane];
#pragma unroll
        for (int k = 0; k < D; ++k) {
            // xs[sub][k]: wave-uniform (broadcast); Ws[lane*64+k]: per-lane row
            acc = fmaf(xs[sub][k], Ws[lane * D + k], acc);
        }
        h[node * D + lane] = acc;
    }
}

// ---------------------------------------------------------------------------
// Kernel 2: scatter-add messages. One wave per edge; lane = feature.
// out[dst[e]][lane] += h[src[e]][lane] * w[e]
// ---------------------------------------------------------------------------
__global__ __launch_bounds__(256) void scatter_kernel(
    const float* __restrict__ h, const int* __restrict__ src,
    const int* __restrict__ dst, const float* __restrict__ w,
    float* __restrict__ out, int n_edges) {
    int tid  = threadIdx.x;
    int e    = blockIdx.x * 4 + (tid >> 6);
    int lane = tid & 63;
    if (e < n_edges) {
        int   s  = src[e];
        int   d  = dst[e];
        float we = w[e];
        float v  = h[s * D + lane] * we;
        atomicAdd(&out[d * D + lane], v);
    }
}

extern "C" void kernel_launch(void* const* d_in, const int* in_sizes, int n_in,
                              void* d_out, int out_size, void* d_ws, size_t ws_size,
                              hipStream_t stream) {
    const float* x   = (const float*)d_in[0];  // [N_NODES, D]
    const int*   src = (const int*)d_in[1];    // [N_EDGES]
    const int*   dst = (const int*)d_in[2];    // [N_EDGES]
    const float* w   = (const float*)d_in[3];  // [N_EDGES]
    const float* W   = (const float*)d_in[4];  // [D, D]
    const float* b   = (const float*)d_in[5];  // [D]
    float*       out = (float*)d_out;          // [N_NODES, D]
    float*       h   = (float*)d_ws;           // [N_NODES, D] scratch

    // out is poisoned to 0xAA before every call -> zero it (stream-ordered).
    hipMemsetAsync(d_out, 0, (size_t)out_size * sizeof(float), stream);

    // h = x @ W^T + b
    int nblocks_lin = (N_NODES + 3) / 4;
    linear_kernel<<<nblocks_lin, 256, 0, stream>>>(x, W, b, h, N_NODES);

    // out[dst] += h[src] * w
    int nblocks_sc = (N_EDGES + 3) / 4;
    scatter_kernel<<<nblocks_sc, 256, 0, stream>>>(h, src, dst, w, out, N_EDGES);
}

// Round 2
// 446.211 us; speedup vs baseline: 1.2037x; 1.2037x over previous
//
#include <hip/hip_runtime.h>

#define N_NODES 100000
#define N_EDGES 1200000
#define D 64
#define EPW 4  // edges per wave in scatter

// ---------------------------------------------------------------------------
// Kernel 1: h = x @ W^T + b.
// 16 nodes per block (4 per wave), lane = output feature o.
// W stored TRANSPOSED in LDS: WsT[k*64+o] -> lane reads consecutive dwords
// (2 lanes/bank, conflict-free). x staged transposed with +1 pad; inner-loop
// x reads are wave-uniform broadcasts.
// ---------------------------------------------------------------------------
__global__ __launch_bounds__(256) void linear_kernel(
    const float* __restrict__ x, const float* __restrict__ W,
    const float* __restrict__ b, float* __restrict__ h, int n_nodes) {
    __shared__ float WsT[D * D];     // WsT[k*64+o] = W[o*64+k]
    __shared__ float xsT[D][17];     // xsT[k][j] = x[node j][k], 16 nodes, +1 pad

    int tid = threadIdx.x;
    // cooperative transposed load of W (float4 global reads, 4 scalar LDS writes)
    for (int i = tid * 4; i < D * D; i += 256 * 4) {
        float4 wv = *reinterpret_cast<const float4*>(&W[i]);
        int o = i >> 6, k = i & 63;
        WsT[(k + 0) * D + o] = wv.x;
        WsT[(k + 1) * D + o] = wv.y;
        WsT[(k + 2) * D + o] = wv.z;
        WsT[(k + 3) * D + o] = wv.w;
    }
    int base = blockIdx.x * 16;
    // stage 16 rows of x, transposed (coalesced global reads; padded LDS writes)
    for (int i = tid; i < 16 * D; i += 256) {
        int r = i >> 6, c = i & 63;
        int node = base + r;
        xsT[c][r] = (node < n_nodes) ? x[node * D + c] : 0.0f;
    }
    __syncthreads();

    int sub = tid >> 6, lane = tid & 63;
    int j0 = sub * 4;
    float bias = b[lane];
    float acc0 = bias, acc1 = bias, acc2 = bias, acc3 = bias;
#pragma unroll
    for (int k = 0; k < D; ++k) {
        float wv = WsT[k * D + lane];            // conflict-free vector read
        acc0 = fmaf(xsT[k][j0 + 0], wv, acc0);   // broadcasts
        acc1 = fmaf(xsT[k][j0 + 1], wv, acc1);
        acc2 = fmaf(xsT[k][j0 + 2], wv, acc2);
        acc3 = fmaf(xsT[k][j0 + 3], wv, acc3);
    }
    int n0 = base + j0;
    if (n0 + 0 < n_nodes) h[(n0 + 0) * D + lane] = acc0;
    if (n0 + 1 < n_nodes) h[(n0 + 1) * D + lane] = acc1;
    if (n0 + 2 < n_nodes) h[(n0 + 2) * D + lane] = acc2;
    if (n0 + 3 < n_nodes) h[(n0 + 3) * D + lane] = acc3;
}

// ---------------------------------------------------------------------------
// Kernel 2: scatter-add. 4 edges per wave, all gathers issued before all
// atomics (memory-level parallelism for latency hiding).
// ---------------------------------------------------------------------------
__global__ __launch_bounds__(256) void scatter_kernel(
    const float* __restrict__ h, const int* __restrict__ src,
    const int* __restrict__ dst, const float* __restrict__ w,
    float* __restrict__ out, int n_edges) {
    int lane = threadIdx.x & 63;
    int wid  = blockIdx.x * 4 + (threadIdx.x >> 6);
    int e0   = wid * EPW;

    int   s[EPW], d[EPW];
    float we[EPW];
#pragma unroll
    for (int j = 0; j < EPW; ++j) {
        int e = e0 + j;
        if (e < n_edges) { s[j] = src[e]; d[j] = dst[e]; we[j] = w[e]; }
        else             { s[j] = -1; d[j] = 0; we[j] = 0.0f; }
    }
    float v[EPW];
#pragma unroll
    for (int j = 0; j < EPW; ++j)
        if (s[j] >= 0) v[j] = h[s[j] * D + lane] * we[j];
#pragma unroll
    for (int j = 0; j < EPW; ++j)
        if (s[j] >= 0) atomicAdd(&out[d[j] * D + lane], v[j]);
}

extern "C" void kernel_launch(void* const* d_in, const int* in_sizes, int n_in,
                              void* d_out, int out_size, void* d_ws, size_t ws_size,
                              hipStream_t stream) {
    const float* x   = (const float*)d_in[0];  // [N_NODES, D]
    const int*   src = (const int*)d_in[1];    // [N_EDGES]
    const int*   dst = (const int*)d_in[2];    // [N_EDGES]
    const float* w   = (const float*)d_in[3];  // [N_EDGES]
    const float* W   = (const float*)d_in[4];  // [D, D]
    const float* b   = (const float*)d_in[5];  // [D]
    float*       out = (float*)d_out;          // [N_NODES, D]
    float*       h   = (float*)d_ws;           // [N_NODES, D] scratch

    hipMemsetAsync(d_out, 0, (size_t)out_size * sizeof(float), stream);

    int nblocks_lin = (N_NODES + 15) / 16;
    linear_kernel<<<nblocks_lin, 256, 0, stream>>>(x, W, b, h, N_NODES);

    int waves = (N_EDGES + EPW - 1) / EPW;
    int nblocks_sc = (waves + 3) / 4;
    scatter_kernel<<<nblocks_sc, 256, 0, stream>>>(h, src, dst, w, out, N_EDGES);
}

// Round 3
// 327.832 us; speedup vs baseline: 1.6384x; 1.3611x over previous
//
#include <hip/hip_runtime.h>

#define N_NODES 100000
#define N_EDGES 1200000
#define D 64
#define SCAN_TILE 2048
#define N_TILES ((N_NODES + SCAN_TILE - 1) / SCAN_TILE)  // 49

// ---- workspace layout (bytes); total ~23.6 MB <= ws (>=25.6 MB) ----
#define OFF_H    0u          // ushort[N_NODES*D]      12.8 MB  (h in bf16)
#define OFF_CSR  12800000u   // int2[N_EDGES]           9.6 MB  ({src, w_bits})
#define OFF_RP   22400000u   // int[N_NODES+1]          rowptr
#define OFF_CUR  22800640u   // int[N_NODES]            fill cursor
#define OFF_DEG  23201280u   // int[N_NODES]            in-degree
#define OFF_SUMS 23601920u   // int[N_TILES]            tile sums

__device__ __forceinline__ unsigned short f2bf(float f) {
    unsigned u = __float_as_uint(f);
    return (unsigned short)((u + 0x7FFFu + ((u >> 16) & 1u)) >> 16);  // RNE
}
__device__ __forceinline__ float bf2f(unsigned short s) {
    return __uint_as_float(((unsigned)s) << 16);
}

// ---------------------------------------------------------------------------
// h = bf16(x @ W^T + b). One wave per block, 16 nodes per block.
// lane = output feature o; W row o lives in 64 VGPRs (loaded once per block);
// x row reads are wave-uniform (node depends only on blockIdx) -> scalar/L1.
// Pure-VALU inner loop: 64 FMA/node, no LDS at all.
// ---------------------------------------------------------------------------
__global__ __launch_bounds__(64) void linear_kernel(
    const float* __restrict__ x, const float* __restrict__ W,
    const float* __restrict__ b, unsigned short* __restrict__ h) {
    int lane = threadIdx.x;
    float4 wr[16];
#pragma unroll
    for (int j = 0; j < 16; ++j)
        wr[j] = *reinterpret_cast<const float4*>(&W[lane * D + j * 4]);
    float bias = b[lane];
    int base = blockIdx.x * 16;

    for (int c = 0; c < 16; ++c) {
        int node = base + c;  // wave-uniform
        const float4* xr = reinterpret_cast<const float4*>(&x[(size_t)node * D]);
        float a0 = bias, a1 = 0.0f, a2 = 0.0f, a3 = 0.0f;
#pragma unroll
        for (int j = 0; j < 16; j += 4) {
            float4 x0 = xr[j], x1 = xr[j + 1], x2 = xr[j + 2], x3 = xr[j + 3];
            a0 = fmaf(wr[j].x, x0.x, fmaf(wr[j].y, x0.y,
                 fmaf(wr[j].z, x0.z, fmaf(wr[j].w, x0.w, a0))));
            a1 = fmaf(wr[j+1].x, x1.x, fmaf(wr[j+1].y, x1.y,
                 fmaf(wr[j+1].z, x1.z, fmaf(wr[j+1].w, x1.w, a1))));
            a2 = fmaf(wr[j+2].x, x2.x, fmaf(wr[j+2].y, x2.y,
                 fmaf(wr[j+2].z, x2.z, fmaf(wr[j+2].w, x2.w, a2))));
            a3 = fmaf(wr[j+3].x, x3.x, fmaf(wr[j+3].y, x3.y,
                 fmaf(wr[j+3].z, x3.z, fmaf(wr[j+3].w, x3.w, a3))));
        }
        h[(size_t)node * D + lane] = f2bf((a0 + a1) + (a2 + a3));
    }
}

// ---------------------------------------------------------------------------
// CSR build: histogram -> 3-pass exclusive scan -> slot fill
// ---------------------------------------------------------------------------
__global__ __launch_bounds__(256) void hist_kernel(
    const int* __restrict__ dst, int* __restrict__ deg) {
    int e = blockIdx.x * 256 + threadIdx.x;
    if (e < N_EDGES) atomicAdd(&deg[dst[e]], 1);
}

__global__ __launch_bounds__(256) void scan1_kernel(
    const int* __restrict__ deg, int* __restrict__ sums) {
    __shared__ int red[256];
    int t = blockIdx.x, tid = threadIdx.x;
    int base = t * SCAN_TILE + tid * 8;
    int s = 0;
#pragma unroll
    for (int j = 0; j < 8; ++j) { int i = base + j; s += (i < N_NODES) ? deg[i] : 0; }
    red[tid] = s; __syncthreads();
    for (int off = 128; off > 0; off >>= 1) {
        if (tid < off) red[tid] += red[tid + off];
        __syncthreads();
    }
    if (tid == 0) sums[t] = red[0];
}

__global__ void scan2_kernel(int* __restrict__ sums, int* __restrict__ rowptr) {
    if (threadIdx.x == 0 && blockIdx.x == 0) {
        int run = 0;
        for (int t = 0; t < N_TILES; ++t) { int v = sums[t]; sums[t] = run; run += v; }
        rowptr[N_NODES] = run;  // == N_EDGES
    }
}

__global__ __launch_bounds__(256) void scan3_kernel(
    const int* __restrict__ deg, const int* __restrict__ sums,
    int* __restrict__ rowptr, int* __restrict__ cursor) {
    __shared__ int sc[256];
    int t = blockIdx.x, tid = threadIdx.x;
    int base = t * SCAN_TILE + tid * 8;
    int d[8]; int tot = 0;
#pragma unroll
    for (int j = 0; j < 8; ++j) {
        int i = base + j;
        d[j] = (i < N_NODES) ? deg[i] : 0;
        tot += d[j];
    }
    sc[tid] = tot; __syncthreads();
    for (int off = 1; off < 256; off <<= 1) {   // inclusive Hillis-Steele
        int v = (tid >= off) ? sc[tid - off] : 0;
        __syncthreads();
        sc[tid] += v;
        __syncthreads();
    }
    int run = sc[tid] - tot + sums[t];          // exclusive + tile base
#pragma unroll
    for (int j = 0; j < 8; ++j) {
        int i = base + j;
        if (i < N_NODES) { rowptr[i] = run; cursor[i] = run; }
        run += d[j];
    }
}

__global__ __launch_bounds__(256) void fill_kernel(
    const int* __restrict__ src, const int* __restrict__ dst,
    const float* __restrict__ w, int* __restrict__ cursor,
    int2* __restrict__ csr) {
    int e = blockIdx.x * 256 + threadIdx.x;
    if (e < N_EDGES) {
        int slot = atomicAdd(&cursor[dst[e]], 1);
        csr[slot] = make_int2(src[e], __float_as_int(w[e]));
    }
}

// ---------------------------------------------------------------------------
// Gather: one wave per dst node, lane = feature. No atomics.
// out[n][lane] = sum_{i in CSR[n]} bf2f(h[src_i][lane]) * w_i
// ---------------------------------------------------------------------------
__global__ __launch_bounds__(256) void gather_kernel(
    const unsigned short* __restrict__ h, const int* __restrict__ rowptr,
    const int2* __restrict__ csr, float* __restrict__ out) {
    int lane = threadIdx.x & 63;
    int node = blockIdx.x * 4 + (threadIdx.x >> 6);
    if (node >= N_NODES) return;
    int i = rowptr[node], end = rowptr[node + 1];
    float acc = 0.0f;
    for (; i + 4 <= end; i += 4) {
        int2 p0 = csr[i], p1 = csr[i + 1], p2 = csr[i + 2], p3 = csr[i + 3];
        float v0 = bf2f(h[(size_t)p0.x * D + lane]);
        float v1 = bf2f(h[(size_t)p1.x * D + lane]);
        float v2 = bf2f(h[(size_t)p2.x * D + lane]);
        float v3 = bf2f(h[(size_t)p3.x * D + lane]);
        acc = fmaf(v0, __int_as_float(p0.y), acc);
        acc = fmaf(v1, __int_as_float(p1.y), acc);
        acc = fmaf(v2, __int_as_float(p2.y), acc);
        acc = fmaf(v3, __int_as_float(p3.y), acc);
    }
    for (; i < end; ++i) {
        int2 p = csr[i];
        acc = fmaf(bf2f(h[(size_t)p.x * D + lane]), __int_as_float(p.y), acc);
    }
    out[(size_t)node * D + lane] = acc;
}

extern "C" void kernel_launch(void* const* d_in, const int* in_sizes, int n_in,
                              void* d_out, int out_size, void* d_ws, size_t ws_size,
                              hipStream_t stream) {
    const float* x   = (const float*)d_in[0];
    const int*   src = (const int*)d_in[1];
    const int*   dst = (const int*)d_in[2];
    const float* w   = (const float*)d_in[3];
    const float* W   = (const float*)d_in[4];
    const float* b   = (const float*)d_in[5];
    float*       out = (float*)d_out;

    char* ws = (char*)d_ws;
    unsigned short* h      = (unsigned short*)(ws + OFF_H);
    int2*           csr    = (int2*)(ws + OFF_CSR);
    int*            rowptr = (int*)(ws + OFF_RP);
    int*            cursor = (int*)(ws + OFF_CUR);
    int*            deg    = (int*)(ws + OFF_DEG);
    int*            sums   = (int*)(ws + OFF_SUMS);

    hipMemsetAsync(deg, 0, (size_t)N_NODES * sizeof(int), stream);

    int eblocks = (N_EDGES + 255) / 256;
    hist_kernel <<<eblocks, 256, 0, stream>>>(dst, deg);
    scan1_kernel<<<N_TILES, 256, 0, stream>>>(deg, sums);
    scan2_kernel<<<1, 64, 0, stream>>>(sums, rowptr);
    scan3_kernel<<<N_TILES, 256, 0, stream>>>(deg, sums, rowptr, cursor);
    linear_kernel<<<N_NODES / 16, 64, 0, stream>>>(x, W, b, h);
    fill_kernel <<<eblocks, 256, 0, stream>>>(src, dst, w, cursor, csr);
    gather_kernel<<<(N_NODES + 3) / 4, 256, 0, stream>>>(h, rowptr, csr, out);
}